// Round 3
// baseline (29515.228 us; speedup 1.0000x reference)
//
#include <hip/hip_runtime.h>

#define N_PTS 40000
#define C_IN 64
#define C_OUT 128
#define K_NN 16
#define M_SAMPLES 10001   // int(40000*0.25)+1

#define NGROUPS 625       // 40000 / 64, exact
#define GRID_DIM 8        // 8x8x8 buckets over [0,10)^3

// Exact reference arithmetic: (dx*dx + dy*dy) + dz*dz, no FMA contraction.
__device__ __forceinline__ float dist3_exact(float dx, float dy, float dz) {
#pragma clang fp contract(off)
  return (dx * dx + dy * dy) + dz * dz;
}

__device__ __forceinline__ int cell_of(float x, float y, float z) {
  int cx = min(GRID_DIM - 1, max(0, (int)(x * 0.8f)));
  int cy = min(GRID_DIM - 1, max(0, (int)(y * 0.8f)));
  int cz = min(GRID_DIM - 1, max(0, (int)(z * 0.8f)));
  return (cx << 6) | (cy << 3) | cz;
}

// ---------------- bucketing prologue ----------------
__global__ void hist_kernel(const float* __restrict__ xyz, int* __restrict__ hist) {
  int p = blockIdx.x * 256 + threadIdx.x;
  if (p < N_PTS) {
    int c = cell_of(xyz[3 * p], xyz[3 * p + 1], xyz[3 * p + 2]);
    atomicAdd(&hist[c], 1);
  }
}

__global__ __launch_bounds__(512) void scan_kernel(const int* __restrict__ hist,
                                                   int* __restrict__ cursor) {
  __shared__ int tmp[512];
  int t = threadIdx.x;
  tmp[t] = hist[t];
  __syncthreads();
  for (int off = 1; off < 512; off <<= 1) {
    int v = tmp[t];
    int u = (t >= off) ? tmp[t - off] : 0;
    __syncthreads();
    tmp[t] = v + u;
    __syncthreads();
  }
  cursor[t] = (t == 0) ? 0 : tmp[t - 1];
}

// pts4[slot] = {x, y, z, bitcast(original_index)}
__global__ void scatter_kernel(const float* __restrict__ xyz, int* __restrict__ cursor,
                               float4* __restrict__ pts4) {
  int p = blockIdx.x * 256 + threadIdx.x;
  if (p < N_PTS) {
    float x = xyz[3 * p], y = xyz[3 * p + 1], z = xyz[3 * p + 2];
    int c = cell_of(x, y, z);
    int pos = atomicAdd(&cursor[c], 1);
    float4 v;
    v.x = x; v.y = y; v.z = z; v.w = __uint_as_float((unsigned)p);
    pts4[pos] = v;
  }
}

// bboxg[g*8 + {0..5}] = {lox,hix,loy,hiy,loz,hiz}
__global__ __launch_bounds__(64) void bbox_kernel(const float4* __restrict__ pts4,
                                                  float* __restrict__ bboxg) {
  int g = blockIdx.x, lane = threadIdx.x;
  float4 P = pts4[g * 64 + lane];
  float lox = P.x, hix = P.x, loy = P.y, hiy = P.y, loz = P.z, hiz = P.z;
#pragma unroll
  for (int off = 32; off > 0; off >>= 1) {
    lox = fminf(lox, __shfl_xor(lox, off)); hix = fmaxf(hix, __shfl_xor(hix, off));
    loy = fminf(loy, __shfl_xor(loy, off)); hiy = fmaxf(hiy, __shfl_xor(hiy, off));
    loz = fminf(loz, __shfl_xor(loz, off)); hiz = fmaxf(hiz, __shfl_xor(hiz, off));
  }
  if (lane == 0) {
    bboxg[g * 8 + 0] = lox; bboxg[g * 8 + 1] = hix;
    bboxg[g * 8 + 2] = loy; bboxg[g * 8 + 3] = hiy;
    bboxg[g * 8 + 4] = loz; bboxg[g * 8 + 5] = hiz;
    bboxg[g * 8 + 6] = 0.f; bboxg[g * 8 + 7] = 0.f;
  }
}

// key = (bits(dist) << 32) | ~idx : u64-max == (dist max, idx min) lexicographic
__device__ __forceinline__ unsigned long long mk_key(float d, unsigned idx) {
  return ((unsigned long long)__float_as_uint(d) << 32) |
         (unsigned long long)(~idx);
}

// ---------------- pruned FPS: single block, 1024 threads, 1 barrier/iter ----
__global__ __launch_bounds__(1024) void fps_kernel(
    const float* __restrict__ xyz, const float4* __restrict__ pts4,
    const float* __restrict__ bboxg, float* __restrict__ nxyz_out) {
  __shared__ float dist_s[N_PTS];                    // 160000 B
  __shared__ unsigned long long red64[2][16];        // 256 B

  const int t = threadIdx.x;
  const int lane = t & 63;
  const int w = t >> 6;  // wave 0..15
  // wave w owns groups g = w + 16*l, l < nloc
  const int nloc = (624 - w) / 16 + 1;  // 40 for w==0 else 39

  for (int i = t; i < N_PTS; i += 1024) dist_s[i] = 1e10f;

  // lane l caches its group's bbox (6 VGPRs) and current (max,argmax) key
  float blox = 0.f, bhix = 0.f, bloy = 0.f, bhiy = 0.f, bloz = 0.f, bhiz = 0.f;
  unsigned long long gkey = mk_key(1e10f, 0u);  // forces all-active at s=0
  if (lane < nloc) {
    int g = w + 16 * lane;
    const float4* b4 = (const float4*)(bboxg + g * 8);
    float4 v0 = b4[0], v1 = b4[1];
    blox = v0.x; bhix = v0.y; bloy = v0.z; bhiy = v0.w;
    bloz = v1.x; bhiz = v1.y;
  }
  float lx = xyz[0], ly = xyz[1], lz = xyz[2];  // center 0 = point 0
  __syncthreads();

  for (int s = 0; s < M_SAMPLES; ++s) {
    const int par = s & 1;
    if (t == 0) {
      nxyz_out[3 * s + 0] = lx;
      nxyz_out[3 * s + 1] = ly;
      nxyz_out[3 * s + 2] = lz;
    }
    // ---- A: wave-local conservative skip test over my groups ----
    bool active = false;
    if (lane < nloc) {
      float mv = __uint_as_float((unsigned)(gkey >> 32));
      float ex = fmaxf(fmaxf(blox - lx, lx - bhix), 0.f);
      float ey = fmaxf(fmaxf(bloy - ly, ly - bhiy), 0.f);
      float ez = fmaxf(fmaxf(bloz - lz, lz - bhiz), 0.f);
      float lb = ex * ex + ey * ey + ez * ez;
      active = !(lb * 0.99999f >= mv);  // skip only when provably no change
    }
    unsigned long long mask = __ballot(active);
    // ---- B: update active groups (whole wave per group), 2-way unrolled ----
    while (mask) {
      int j0 = __ffsll((long long)mask) - 1;
      mask &= mask - 1;
      int j1 = -1;
      if (mask) { j1 = __ffsll((long long)mask) - 1; mask &= mask - 1; }
      int s0 = (w + 16 * j0) * 64 + lane;
      float4 P0 = pts4[s0];
      float od0 = dist_s[s0];
      int s1 = 0;
      float4 P1;
      float od1 = 0.f;
      if (j1 >= 0) {
        s1 = (w + 16 * j1) * 64 + lane;
        P1 = pts4[s1];
        od1 = dist_s[s1];
      }
      {
        float dx, dy, dz;
        {
#pragma clang fp contract(off)
          dx = P0.x - lx; dy = P0.y - ly; dz = P0.z - lz;
        }
        float d = dist3_exact(dx, dy, dz);
        float nd = fminf(od0, d);
        dist_s[s0] = nd;
        unsigned long long k = mk_key(nd, __float_as_uint(P0.w));
#pragma unroll
        for (int off = 32; off > 0; off >>= 1) {
          unsigned long long ok = __shfl_xor(k, off);
          if (ok > k) k = ok;
        }
        if (lane == j0) gkey = k;
      }
      if (j1 >= 0) {
        float dx, dy, dz;
        {
#pragma clang fp contract(off)
          dx = P1.x - lx; dy = P1.y - ly; dz = P1.z - lz;
        }
        float d = dist3_exact(dx, dy, dz);
        float nd = fminf(od1, d);
        dist_s[s1] = nd;
        unsigned long long k = mk_key(nd, __float_as_uint(P1.w));
#pragma unroll
        for (int off = 32; off > 0; off >>= 1) {
          unsigned long long ok = __shfl_xor(k, off);
          if (ok > k) k = ok;
        }
        if (lane == j1) gkey = k;
      }
    }
    // ---- C: global winner = max over all group keys ----
    unsigned long long c = (lane < nloc) ? gkey : 0ull;
#pragma unroll
    for (int off = 32; off > 0; off >>= 1) {
      unsigned long long ok = __shfl_xor(c, off);
      if (ok > c) c = ok;
    }
    if (lane == 0) red64[par][w] = c;
    __syncthreads();  // the ONLY barrier per iteration
    unsigned long long best = red64[par][0];
#pragma unroll
    for (int i = 1; i < 16; ++i) {
      unsigned long long ok = red64[par][i];
      if (ok > best) best = ok;
    }
    int bi = (int)(~(unsigned)best);
    lx = xyz[3 * bi + 0];  // broadcast load, L2-hot
    ly = xyz[3 * bi + 1];
    lz = xyz[3 * bi + 2];
  }
}

// ---------------- KNN: one wave per center ----------------
#define KNN_TILE 2048

__device__ __forceinline__ float knn_dist_exact(float sn, float cx, float cy,
                                                float cz, float x, float y,
                                                float z) {
#pragma clang fp contract(off)
  float sx = (x * x + y * y) + z * z;
  float dot = (cx * x + cy * y) + cz * z;
  return (sn - 2.0f * dot) + sx;
}

__global__ __launch_bounds__(256) void knn_kernel(
    const float* __restrict__ xyz, const float* __restrict__ nxyz,
    int* __restrict__ knn_out) {
  __shared__ float txyz[KNN_TILE * 3];
  const int lane = threadIdx.x & 63;
  const int wv = threadIdx.x >> 6;
  const int m = blockIdx.x * 4 + wv;
  const bool active = (m < M_SAMPLES);

  float cx = 0.f, cy = 0.f, cz = 0.f;
  if (active) {
    cx = nxyz[3 * m + 0]; cy = nxyz[3 * m + 1]; cz = nxyz[3 * m + 2];
  }
  float sn;
  {
#pragma clang fp contract(off)
    sn = (cx * cx + cy * cy) + cz * cz;
  }

  float hd[K_NN];
  int hi[K_NN];
#pragma unroll
  for (int i = 0; i < K_NN; ++i) { hd[i] = 3.4e38f; hi[i] = 0x7fffffff; }

  for (int base = 0; base < N_PTS; base += KNN_TILE) {
    const int cnt = min(KNN_TILE, N_PTS - base);
    __syncthreads();
    {
      const float4* src4 = (const float4*)(xyz + (size_t)base * 3);
      float4* dst4 = (float4*)txyz;
      const int n4 = (cnt * 3) >> 2;
      for (int i = threadIdx.x; i < n4; i += 256) dst4[i] = src4[i];
    }
    __syncthreads();
    for (int p = lane; p < cnt; p += 64) {
      float x = txyz[3 * p + 0], y = txyz[3 * p + 1], z = txyz[3 * p + 2];
      float d = knn_dist_exact(sn, cx, cy, cz, x, y, z);
      int gi = base + p;
      if (d < hd[K_NN - 1] || (d == hd[K_NN - 1] && gi < hi[K_NN - 1])) {
        hd[K_NN - 1] = d;
        hi[K_NN - 1] = gi;
#pragma unroll
        for (int i = K_NN - 1; i > 0; --i) {
          bool sw = (hd[i] < hd[i - 1]) ||
                    (hd[i] == hd[i - 1] && hi[i] < hi[i - 1]);
          if (sw) {
            float td = hd[i]; hd[i] = hd[i - 1]; hd[i - 1] = td;
            int ti = hi[i]; hi[i] = hi[i - 1]; hi[i - 1] = ti;
          }
        }
      }
    }
  }

  int keep = 0;
#pragma unroll 1
  for (int r = 0; r < K_NN; ++r) {
    float d0 = hd[0];
    int i0 = hi[0];
    int l0 = lane;
#pragma unroll
    for (int off = 32; off > 0; off >>= 1) {
      float od = __shfl_xor(d0, off);
      int oi = __shfl_xor(i0, off);
      int ol = __shfl_xor(l0, off);
      if (od < d0 || (od == d0 && oi < i0)) { d0 = od; i0 = oi; l0 = ol; }
    }
    if (lane == r) keep = i0;
    if (lane == l0) {
#pragma unroll
      for (int i = 0; i < K_NN - 1; ++i) { hd[i] = hd[i + 1]; hi[i] = hi[i + 1]; }
      hd[K_NN - 1] = 3.4e38f;
      hi[K_NN - 1] = 0x7fffffff;
    }
  }
  if (active && lane < K_NN) knn_out[m * K_NN + lane] = keep;
}

// -------- gather + LayerNorm + Linear + maxpool: one block per center --------
__global__ __launch_bounds__(128) void head_kernel(
    const float* __restrict__ feats, const int* __restrict__ knn,
    const float* __restrict__ lnw, const float* __restrict__ lnb,
    const float* __restrict__ W, float* __restrict__ out,
    float* __restrict__ noff) {
  const int m = blockIdx.x;
  const int t = threadIdx.x;
  __shared__ float g[K_NN][68];
  __shared__ float mu_s[K_NN], rs_s[K_NN];

  for (int q = t; q < 256; q += 128) {
    int k = q >> 4, c4 = q & 15;
    int src = knn[m * K_NN + k];
    float4 v = ((const float4*)(feats + (size_t)src * C_IN))[c4];
    g[k][c4 * 4 + 0] = v.x;
    g[k][c4 * 4 + 1] = v.y;
    g[k][c4 * 4 + 2] = v.z;
    g[k][c4 * 4 + 3] = v.w;
  }
  __syncthreads();
  if (t < K_NN) {
    float s = 0.f;
    for (int c = 0; c < C_IN; ++c) s += g[t][c];
    float mu = s * (1.0f / 64.0f);
    float v = 0.f;
    for (int c = 0; c < C_IN; ++c) {
      float d = g[t][c] - mu;
      v += d * d;
    }
    v *= (1.0f / 64.0f);
    mu_s[t] = mu;
    rs_s[t] = rsqrtf(v + 1e-5f);
  }
  __syncthreads();
  for (int q = t; q < K_NN * C_IN; q += 128) {
    int k = q >> 6, c = q & 63;
    g[k][c] = (g[k][c] - mu_s[k]) * rs_s[k] * lnw[c] + lnb[c];
  }
  __syncthreads();
  float acc[K_NN];
#pragma unroll
  for (int k = 0; k < K_NN; ++k) acc[k] = 0.f;
  for (int c = 0; c < C_IN; ++c) {
    float wv = W[c * C_OUT + t];
#pragma unroll
    for (int k = 0; k < K_NN; ++k) acc[k] = fmaf(g[k][c], wv, acc[k]);
  }
  float mx = acc[0];
#pragma unroll
  for (int k = 1; k < K_NN; ++k) mx = fmaxf(mx, acc[k]);
  out[(size_t)m * C_OUT + t] = mx;

  if (m == 0 && t == 0) noff[0] = (float)M_SAMPLES;
}

extern "C" void kernel_launch(void* const* d_in, const int* in_sizes, int n_in,
                              void* d_out, int out_size, void* d_ws,
                              size_t ws_size, hipStream_t stream) {
  const float* feats = (const float*)d_in[0];
  const float* xyz = (const float*)d_in[1];
  const float* lnw = (const float*)d_in[3];
  const float* lnb = (const float*)d_in[4];
  const float* W = (const float*)d_in[5];

  float* out = (float*)d_out;
  float* nxyz = out + (size_t)M_SAMPLES * C_OUT;
  float* noff = nxyz + (size_t)M_SAMPLES * 3;

  char* ws = (char*)d_ws;
  int* hist = (int*)(ws + 0);                 // 512 ints
  int* cursor = (int*)(ws + 2048);            // 512 ints
  float4* pts4 = (float4*)(ws + 4096);        // 40000 float4 = 640000 B
  float* bboxg = (float*)(ws + 644096);       // 625*8 f = 20000 B
  int* knn = (int*)(ws + 664096);             // 10001*16 ints

  hipMemsetAsync(hist, 0, 512 * sizeof(int), stream);
  hist_kernel<<<(N_PTS + 255) / 256, 256, 0, stream>>>(xyz, hist);
  scan_kernel<<<1, 512, 0, stream>>>(hist, cursor);
  scatter_kernel<<<(N_PTS + 255) / 256, 256, 0, stream>>>(xyz, cursor, pts4);
  bbox_kernel<<<NGROUPS, 64, 0, stream>>>(pts4, bboxg);
  fps_kernel<<<1, 1024, 0, stream>>>(xyz, pts4, bboxg, nxyz);
  knn_kernel<<<(M_SAMPLES + 3) / 4, 256, 0, stream>>>(xyz, nxyz, knn);
  head_kernel<<<M_SAMPLES, 128, 0, stream>>>(feats, knn, lnw, lnb, W, out, noff);
}